// Round 1
// baseline (30217.905 us; speedup 1.0000x reference)
//
#include <hip/hip_runtime.h>

#define TT 8192
#define HH 200
#define G4 800      // 4*H
#define NB 8        // blocks per recurrence
#define NPB 25      // neurons per block
#define GPB 100     // gate rows per block

__device__ __forceinline__ float sigmoidf_(float x) {
    return 1.0f / (1.0f + __expf(-x));
}
__device__ __forceinline__ float tanhf_(float x) {
    // overflow-safe: e^{2|x|} may be inf -> r -> 1
    float e = __expf(2.0f * fabsf(x));
    float r = 1.0f - 2.0f / (e + 1.0f);
    return copysignf(r, x);
}

// One sequential LSTM recurrence, 8 blocks, gate-partitioned (no cross-block
// reduction). Weights resident in VGPRs. Per-step cross-block h broadcast via
// tagged {float,tag} 8B agent-scope atomics (tag rides with data: one L3 RTT).
template<int LAYER>
__global__ __launch_bounds__(256)
void lstm_seq(const float* __restrict__ Whh,
              const float* __restrict__ bih, const float* __restrict__ bhh,
              const float* __restrict__ xin,   // L0 only: x[T]
              const float* __restrict__ Wih0,  // L0 only: [800] (D=1)
              const float* __restrict__ pre1,  // L1 only: [T][800] incl. bias
              unsigned long long* __restrict__ hb,  // tagged pairs [T][200]
              const float* __restrict__ Wout, const float* __restrict__ bout,
              float* __restrict__ out)
{
    const int wblk = blockIdx.x;
    const int tid  = threadIdx.x;
    const int lg   = tid >> 1;          // local gate 0..127 (100 used)
    const int half = tid & 1;           // k-half: [0,100) or [100,200)
    const bool active = lg < GPB;
    const int q  = lg / NPB;            // gate quadrant i/f/g/o
    const int ln = lg % NPB;            // local neuron
    const int nb = wblk * NPB;          // neuron base
    const int row = q * HH + nb + ln;   // global gate row in [0,800)

    __shared__ float h_lds[HH];
    __shared__ float s_lds[GPB];
    __shared__ float xs[(LAYER == 0) ? TT : 1];   // 32KB for layer 0

    float w[100];
    float wih = 0.f, bs = 0.f;
    if (active) {
        const float* wr = Whh + (size_t)row * HH + half * 100;
        #pragma unroll
        for (int j = 0; j < 100; ++j) w[j] = wr[j];
        if (half == 0) {
            if constexpr (LAYER == 0) {
                bs  = bih[row] + bhh[row];
                wih = Wih0[row];
            }
        }
    }
    if constexpr (LAYER == 0) {
        for (int i = tid; i < TT; i += 256) xs[i] = xin[i];
    }
    if (tid < HH) h_lds[tid] = 0.f;

    float c = 0.f;        // cell state, owned by threads tid<25
    float p_next = 0.f;   // prefetched pre1[t]
    if constexpr (LAYER == 1) {
        if (active && half == 0) p_next = pre1[row];   // t=0
    }
    __syncthreads();

    for (int t = 0; t < TT; ++t) {
        float p_cur = 0.f;
        if constexpr (LAYER == 1) {
            p_cur = p_next;
            // prefetch next step's pre-activation (off critical path)
            if (active && half == 0 && t + 1 < TT)
                p_next = pre1[(size_t)(t + 1) * G4 + row];
        }

        // ---- recurrent matvec: 100 MACs/thread, weights in VGPRs ----
        float a0 = 0.f, a1 = 0.f, a2 = 0.f, a3 = 0.f;
        if (active) {
            const float* hl = h_lds + half * 100;
            #pragma unroll
            for (int j = 0; j < 100; j += 4) {
                a0 += w[j]     * hl[j];
                a1 += w[j + 1] * hl[j + 1];
                a2 += w[j + 2] * hl[j + 2];
                a3 += w[j + 3] * hl[j + 3];
            }
        }
        float sum = (a0 + a1) + (a2 + a3);
        sum += __shfl_xor(sum, 1);   // pair (half=0, half=1) -> full dot
        if (active && half == 0) {
            float p;
            if constexpr (LAYER == 0) p = xs[t] * wih + bs;
            else                      p = p_cur;
            s_lds[lg] = sum + p;
        }
        __syncthreads();

        // ---- gate nonlinearity + state update (25 threads) ----
        if (tid < NPB) {
            float si = s_lds[tid];
            float sf = s_lds[NPB + tid];
            float sg = s_lds[2 * NPB + tid];
            float so = s_lds[3 * NPB + tid];
            float ig = sigmoidf_(si);
            float fg = sigmoidf_(sf);
            float gg = tanhf_(sg);
            float og = sigmoidf_(so);
            c = fg * c + ig * gg;
            float h = og * tanhf_(c);
            unsigned long long pk =
                ((unsigned long long)(unsigned)(t + 1) << 32) |
                (unsigned long long)__float_as_uint(h);
            __hip_atomic_store(&hb[(size_t)t * HH + nb + tid], pk,
                               __ATOMIC_RELAXED, __HIP_MEMORY_SCOPE_AGENT);
        }

        // ---- poll tagged pairs from all blocks; data rides with tag ----
        if (tid < HH) {
            unsigned long long v;
            unsigned long long* pp = &hb[(size_t)t * HH + tid];
            do {
                v = __hip_atomic_load(pp, __ATOMIC_RELAXED,
                                      __HIP_MEMORY_SCOPE_AGENT);
            } while ((unsigned)(v >> 32) != (unsigned)(t + 1));
            h_lds[tid] = __uint_as_float((unsigned)v);
        }
        __syncthreads();
    }

    // ---- linear head on final h1 ----
    if constexpr (LAYER == 1) {
        if (wblk == 0 && tid < 64) {
            float s = 0.f;
            for (int j = tid; j < HH; j += 64) s += h_lds[j] * Wout[j];
            #pragma unroll
            for (int off = 32; off > 0; off >>= 1) s += __shfl_down(s, off);
            if (tid == 0) out[0] = s + bout[0];
        }
    }
}

// Parallel pre-activation GEMM: pre1[t][row] = dot(h0[t], Wih1[row]) + b1[row]
// Grid: 8 gate-blocks x 32 time-chunks = 256 blocks. Weights in VGPRs.
__global__ __launch_bounds__(256)
void pre1_gemm(const unsigned long long* __restrict__ hbA,
               const float* __restrict__ Wih1,
               const float* __restrict__ bih1, const float* __restrict__ bhh1,
               float* __restrict__ pre1)
{
    const int gb  = blockIdx.x & 7;
    const int tc  = blockIdx.x >> 3;    // 0..31
    const int tid = threadIdx.x;
    const int lg   = tid >> 1;
    const int half = tid & 1;
    const bool active = lg < GPB;
    const int q  = lg / NPB;
    const int ln = lg % NPB;
    const int nb = gb * NPB;
    const int row = q * HH + nb + ln;

    __shared__ float h_lds[HH];
    float w[100];
    float bs = 0.f;
    if (active) {
        const float* wr = Wih1 + (size_t)row * HH + half * 100;
        #pragma unroll
        for (int j = 0; j < 100; ++j) w[j] = wr[j];
        if (half == 0) bs = bih1[row] + bhh1[row];
    }
    const int tlen = TT / 32;
    const int t0 = tc * tlen;
    for (int t = t0; t < t0 + tlen; ++t) {
        __syncthreads();
        if (tid < HH)
            h_lds[tid] = __uint_as_float((unsigned)hbA[(size_t)t * HH + tid]);
        __syncthreads();
        float a0 = 0.f, a1 = 0.f, a2 = 0.f, a3 = 0.f;
        if (active) {
            const float* hl = h_lds + half * 100;
            #pragma unroll
            for (int j = 0; j < 100; j += 4) {
                a0 += w[j]     * hl[j];
                a1 += w[j + 1] * hl[j + 1];
                a2 += w[j + 2] * hl[j + 2];
                a3 += w[j + 3] * hl[j + 3];
            }
        }
        float sum = (a0 + a1) + (a2 + a3);
        sum += __shfl_xor(sum, 1);
        if (active && half == 0)
            pre1[(size_t)t * G4 + row] = sum + bs;
    }
}

extern "C" void kernel_launch(void* const* d_in, const int* in_sizes, int n_in,
                              void* d_out, int out_size, void* d_ws, size_t ws_size,
                              hipStream_t stream) {
    const float* x    = (const float*)d_in[0];
    const float* Wih0 = (const float*)d_in[1];
    const float* Whh0 = (const float*)d_in[2];
    const float* bih0 = (const float*)d_in[3];
    const float* bhh0 = (const float*)d_in[4];
    const float* Wih1 = (const float*)d_in[5];
    const float* Whh1 = (const float*)d_in[6];
    const float* bih1 = (const float*)d_in[7];
    const float* bhh1 = (const float*)d_in[8];
    const float* Wout = (const float*)d_in[9];
    const float* bout = (const float*)d_in[10];
    float* out = (float*)d_out;

    char* ws = (char*)d_ws;
    // layout: hbA pairs 13,107,200 | hbC pairs 13,107,200 | pre1 26,214,400
    unsigned long long* hbA = (unsigned long long*)ws;
    unsigned long long* hbC = (unsigned long long*)(ws + 13107200);
    float* pre1             = (float*)(ws + 26214400);

    // clear tag buffers each call (graph-safe, no cross-replay state)
    hipMemsetAsync(ws, 0, 26214400, stream);

    hipLaunchKernelGGL((lstm_seq<0>), dim3(NB), dim3(256), 0, stream,
        Whh0, bih0, bhh0, x, Wih0, (const float*)nullptr, hbA,
        (const float*)nullptr, (const float*)nullptr, (float*)nullptr);

    hipLaunchKernelGGL(pre1_gemm, dim3(256), dim3(256), 0, stream,
        hbA, Wih1, bih1, bhh1, pre1);

    hipLaunchKernelGGL((lstm_seq<1>), dim3(NB), dim3(256), 0, stream,
        Whh1, bih1, bhh1, (const float*)nullptr, (const float*)nullptr, pre1,
        hbC, Wout, bout, out);
}